// Round 9
// baseline (322.279 us; speedup 1.0000x reference)
//
#include <hip/hip_runtime.h>

#define D 128
#define SCAN_B 256

typedef __attribute__((ext_vector_type(8))) short bf16x8;
typedef __attribute__((ext_vector_type(4))) float f32x4;

__device__ __forceinline__ unsigned short f2bf(float f) {
    unsigned u = __float_as_uint(f);
    unsigned r = u + 0x7FFFu + ((u >> 16) & 1u);  // RNE
    return (unsigned short)(r >> 16);
}
__device__ __forceinline__ float bf2f(unsigned short h) {
    return __uint_as_float(((unsigned)h) << 16);
}

// ---- degree count ----
__global__ void count_kernel(const int* __restrict__ ei, int E, int* __restrict__ cnt) {
    int t = blockIdx.x * blockDim.x + threadIdx.x;
    if (t < E) atomicAdd(&cnt[ei[E + t]], 1);
}

// ---- hierarchical exclusive scan ----
__global__ void scan_pass1(const int* __restrict__ cnt, int* __restrict__ rs,
                           int* __restrict__ bsum, int N) {
    __shared__ int lds[SCAN_B];
    int tid = threadIdx.x;
    int i = blockIdx.x * SCAN_B + tid;
    int v = (i < N) ? cnt[i] : 0;
    lds[tid] = v;
    __syncthreads();
    for (int o = 1; o < SCAN_B; o <<= 1) {
        int t = (tid >= o) ? lds[tid - o] : 0;
        __syncthreads();
        lds[tid] += t;
        __syncthreads();
    }
    if (i < N) rs[i] = lds[tid] - v;
    if (tid == SCAN_B - 1) bsum[blockIdx.x] = lds[tid];
}

__global__ void scan_pass2(int* __restrict__ bsum, int nb) {
    __shared__ int lds[SCAN_B];
    int tid = threadIdx.x;
    int v = (tid < nb) ? bsum[tid] : 0;
    lds[tid] = v;
    __syncthreads();
    for (int o = 1; o < SCAN_B; o <<= 1) {
        int t = (tid >= o) ? lds[tid - o] : 0;
        __syncthreads();
        lds[tid] += t;
        __syncthreads();
    }
    if (tid < nb) bsum[tid] = lds[tid] - v;
}

__global__ void scan_pass3(int* __restrict__ rs, int* __restrict__ cursor,
                           const int* __restrict__ bsum, const int* __restrict__ cnt,
                           float* __restrict__ inv, int N) {
    int i = blockIdx.x * SCAN_B + threadIdx.x;
    if (i < N) {
        int v = rs[i] + bsum[blockIdx.x];
        rs[i] = v;
        cursor[i] = v;
        inv[i] = 1.0f / (float)max(cnt[i], 1);
    }
}

__global__ void fill_kernel(const int* __restrict__ ei, int E,
                            int* __restrict__ cursor, int* __restrict__ csr) {
    int e = blockIdx.x * blockDim.x + threadIdx.x;
    if (e < E) {
        int src = ei[e], dst = ei[E + e];
        int pos = atomicAdd(&cursor[dst], 1);
        csr[pos] = src;
    }
}

// ---- gather-mean aggregate: 32 lanes per node, 8-way unrolled ----
__global__ void aggregate_kernel(const float* __restrict__ x, const int* __restrict__ csr,
                                 const int* __restrict__ rs, const int* __restrict__ cnt,
                                 const float* __restrict__ inv, float* __restrict__ agg,
                                 int N) {
    int t = blockIdx.x * blockDim.x + threadIdx.x;
    int node = t >> 5;
    int c = t & 31;
    if (node >= N) return;
    int deg = cnt[node];
    int st = rs[node];
    const float4* x4 = (const float4*)x;
    float4 s0 = make_float4(0.f, 0.f, 0.f, 0.f);
    float4 s1 = make_float4(0.f, 0.f, 0.f, 0.f);
    int i = 0;
    for (; i + 8 <= deg; i += 8) {
        int n0 = csr[st + i + 0], n1 = csr[st + i + 1];
        int n2 = csr[st + i + 2], n3 = csr[st + i + 3];
        int n4 = csr[st + i + 4], n5 = csr[st + i + 5];
        int n6 = csr[st + i + 6], n7 = csr[st + i + 7];
        float4 v0 = x4[(size_t)n0 * 32 + c];
        float4 v1 = x4[(size_t)n1 * 32 + c];
        float4 v2 = x4[(size_t)n2 * 32 + c];
        float4 v3 = x4[(size_t)n3 * 32 + c];
        float4 v4 = x4[(size_t)n4 * 32 + c];
        float4 v5 = x4[(size_t)n5 * 32 + c];
        float4 v6 = x4[(size_t)n6 * 32 + c];
        float4 v7 = x4[(size_t)n7 * 32 + c];
        s0.x += (v0.x + v1.x) + (v2.x + v3.x);
        s0.y += (v0.y + v1.y) + (v2.y + v3.y);
        s0.z += (v0.z + v1.z) + (v2.z + v3.z);
        s0.w += (v0.w + v1.w) + (v2.w + v3.w);
        s1.x += (v4.x + v5.x) + (v6.x + v7.x);
        s1.y += (v4.y + v5.y) + (v6.y + v7.y);
        s1.z += (v4.z + v5.z) + (v6.z + v7.z);
        s1.w += (v4.w + v5.w) + (v6.w + v7.w);
    }
    for (; i + 4 <= deg; i += 4) {
        int n0 = csr[st + i + 0], n1 = csr[st + i + 1];
        int n2 = csr[st + i + 2], n3 = csr[st + i + 3];
        float4 v0 = x4[(size_t)n0 * 32 + c];
        float4 v1 = x4[(size_t)n1 * 32 + c];
        float4 v2 = x4[(size_t)n2 * 32 + c];
        float4 v3 = x4[(size_t)n3 * 32 + c];
        s0.x += v0.x + v1.x; s0.y += v0.y + v1.y;
        s0.z += v0.z + v1.z; s0.w += v0.w + v1.w;
        s1.x += v2.x + v3.x; s1.y += v2.y + v3.y;
        s1.z += v2.z + v3.z; s1.w += v2.w + v3.w;
    }
    for (; i < deg; i++) {
        int n0 = csr[st + i];
        float4 v0 = x4[(size_t)n0 * 32 + c];
        s0.x += v0.x; s0.y += v0.y; s0.z += v0.z; s0.w += v0.w;
    }
    float iv = inv[node];
    float4 s = make_float4((s0.x + s1.x) * iv, (s0.y + s1.y) * iv,
                           (s0.z + s1.z) * iv, (s0.w + s1.w) * iv);
    ((float4*)agg)[(size_t)node * 32 + c] = s;
}

// ---- weight pack: fp32 [128k x 128n] -> bf16 hi/lo fragment-ordered ----
// element (ks, t, lane, j) = W[ks*32 + (lane>>4)*8 + j][t*16 + (lane&15)]
__global__ void pack_kernel(const float* __restrict__ W1l, const float* __restrict__ W1r,
                            const float* __restrict__ W2l, const float* __restrict__ W2r,
                            const float* __restrict__ Wf, unsigned short* __restrict__ pw) {
    int idx = blockIdx.x * blockDim.x + threadIdx.x;
    if (idx >= 5 * 2048) return;
    int w = idx >> 11;
    int r = idx & 2047;
    int ks = r >> 9;
    int t = (r >> 6) & 7;
    int lane = r & 63;
    int q = lane >> 4, n = lane & 15;
    const float* W = (w == 0) ? W1l : (w == 1) ? W1r : (w == 2) ? W2l : (w == 3) ? W2r : Wf;
    unsigned short* dh = pw + (size_t)w * 32768;
    unsigned short* dl = dh + 16384;
    int off = ((ks * 8 + t) * 64 + lane) * 8;
#pragma unroll
    for (int j = 0; j < 8; j++) {
        float v = W[(size_t)(ks * 32 + q * 8 + j) * D + t * 16 + n];
        unsigned short hb = f2bf(v);
        dh[off + j] = hb;
        dl[off + j] = f2bf(v - bf2f(hb));
    }
}

__device__ __forceinline__ void split8(const float* av, bf16x8& hi, bf16x8& lo) {
#pragma unroll
    for (int j = 0; j < 8; j++) {
        unsigned short hb = f2bf(av[j]);
        hi[j] = (short)hb;
        lo[j] = (short)f2bf(av[j] - bf2f(hb));
    }
}

// ---- barrier-free streaming MFMA GEMM ----
// block: 256 thr = 4 waves; each wave owns 32 rows (two 16-row groups); BN=128; K=256.
// A-fragments loaded directly from row-major global (no LDS, no barriers in main loop).
// C = relu(l2norm([agg|x] @ [Wl;Wr] + bl)) [@ Wf + bf]
template <int FUSE_FC>
__global__ __launch_bounds__(256) void mfma_gemm(
        const float* __restrict__ Aagg, const float* __restrict__ Ax,
        const unsigned short* __restrict__ W0h, const unsigned short* __restrict__ W0lo,
        const unsigned short* __restrict__ W1h, const unsigned short* __restrict__ W1lo,
        const float* __restrict__ bias,
        const unsigned short* __restrict__ Wfh, const unsigned short* __restrict__ Wflo,
        const float* __restrict__ bfin,
        float* __restrict__ out, int N) {
    __shared__ unsigned short Hs[FUSE_FC ? 4 * 4096 : 4];  // 8 KB/wave (hi 2048 + lo 2048)

    const int tid = threadIdx.x;
    const int lane = tid & 63;
    const int wave = tid >> 6;
    const int c = lane & 15;   // A row-in-tile / C col-in-tile
    const int q = lane >> 4;   // quad
    const int R = blockIdx.x * 128 + wave * 32;   // wave's first row

    int row0 = R + c;       if (row0 >= N) row0 = N - 1;
    int row1 = R + 16 + c;  if (row1 >= N) row1 = N - 1;
    const size_t a0_base = (size_t)row0 * D;
    const size_t a1_base = (size_t)row1 * D;

    f32x4 acc[2][8];
#pragma unroll
    for (int g = 0; g < 2; g++)
#pragma unroll
        for (int t = 0; t < 8; t++)
#pragma unroll
            for (int r = 0; r < 4; r++) acc[g][t][r] = 0.0f;

#pragma unroll
    for (int ks = 0; ks < 8; ks++) {
        const float* Asrc = (ks < 4) ? Aagg : Ax;
        const int kl = ks & 3;
        const int koff = kl * 32 + q * 8;
        // direct A-fragment loads (row-major): 8 floats per group
        float av0[8], av1[8];
        *((float4*)&av0[0]) = *((const float4*)(Asrc + a0_base + koff));
        *((float4*)&av0[4]) = *((const float4*)(Asrc + a0_base + koff + 4));
        *((float4*)&av1[0]) = *((const float4*)(Asrc + a1_base + koff));
        *((float4*)&av1[4]) = *((const float4*)(Asrc + a1_base + koff + 4));
        bf16x8 ah0, al0, ah1, al1;
        split8(av0, ah0, al0);
        split8(av1, ah1, al1);

        const uint4* Wh4 = (const uint4*)((ks < 4) ? W0h : W1h);
        const uint4* Wl4 = (const uint4*)((ks < 4) ? W0lo : W1lo);
#pragma unroll
        for (int t = 0; t < 8; t++) {
            int fi = (kl * 8 + t) * 64 + lane;
            bf16x8 bh = __builtin_bit_cast(bf16x8, Wh4[fi]);
            bf16x8 blo = __builtin_bit_cast(bf16x8, Wl4[fi]);
            acc[0][t] = __builtin_amdgcn_mfma_f32_16x16x32_bf16(ah0, bh, acc[0][t], 0, 0, 0);
            acc[0][t] = __builtin_amdgcn_mfma_f32_16x16x32_bf16(al0, bh, acc[0][t], 0, 0, 0);
            acc[0][t] = __builtin_amdgcn_mfma_f32_16x16x32_bf16(ah0, blo, acc[0][t], 0, 0, 0);
            acc[1][t] = __builtin_amdgcn_mfma_f32_16x16x32_bf16(ah1, bh, acc[1][t], 0, 0, 0);
            acc[1][t] = __builtin_amdgcn_mfma_f32_16x16x32_bf16(al1, bh, acc[1][t], 0, 0, 0);
            acc[1][t] = __builtin_amdgcn_mfma_f32_16x16x32_bf16(ah1, blo, acc[1][t], 0, 0, 0);
        }
    }

    // epilogue: bias + per-row L2 norm + relu  (C layout: col=t*16+c, row=q*4+r)
#pragma unroll
    for (int g = 0; g < 2; g++) {
#pragma unroll
        for (int t = 0; t < 8; t++) {
            float bv = bias[t * 16 + c];
#pragma unroll
            for (int r = 0; r < 4; r++) acc[g][t][r] += bv;
        }
#pragma unroll
        for (int r = 0; r < 4; r++) {
            float v = 0.0f;
#pragma unroll
            for (int t = 0; t < 8; t++) v += acc[g][t][r] * acc[g][t][r];
            v += __shfl_xor(v, 1, 16);
            v += __shfl_xor(v, 2, 16);
            v += __shfl_xor(v, 4, 16);
            v += __shfl_xor(v, 8, 16);
            float rn = 1.0f / fmaxf(sqrtf(v), 1e-12f);
#pragma unroll
            for (int t = 0; t < 8; t++) acc[g][t][r] = fmaxf(acc[g][t][r] * rn, 0.0f);
        }
    }

    if (!FUSE_FC) {
#pragma unroll
        for (int g = 0; g < 2; g++)
#pragma unroll
            for (int t = 0; t < 8; t++)
#pragma unroll
                for (int r = 0; r < 4; r++) {
                    int row = R + g * 16 + q * 4 + r;
                    if (row < N) out[(size_t)row * D + t * 16 + c] = acc[g][t][r];
                }
        return;
    }

    // FC: per-wave LDS h-transform (C layout -> A-operand layout), group-at-a-time.
    // Hw is wave-private; DS pipe is in-order per wave, so no barriers needed.
    unsigned short* Hw = &Hs[wave * 4096];
    bf16x8 ah2[2][4], al2[2][4];
#pragma unroll
    for (int g = 0; g < 2; g++) {
#pragma unroll
        for (int t = 0; t < 8; t++)
#pragma unroll
            for (int r = 0; r < 4; r++) {
                int row = q * 4 + r;
                int col = t * 16 + c;
                int ks2 = col >> 5, c32 = col & 31;
                int off = ((ks2 * 64) + (c32 >> 3) * 16 + row) * 8 + (c32 & 7);
                float hv = acc[g][t][r];
                unsigned short hb = f2bf(hv);
                Hw[off] = hb;
                Hw[2048 + off] = f2bf(hv - bf2f(hb));
            }
#pragma unroll
        for (int ks2 = 0; ks2 < 4; ks2++) {
            ah2[g][ks2] = __builtin_bit_cast(bf16x8, ((const uint4*)Hw)[ks2 * 64 + lane]);
            al2[g][ks2] = __builtin_bit_cast(bf16x8, ((const uint4*)(Hw + 2048))[ks2 * 64 + lane]);
        }
    }

    f32x4 acc2[2][8];
#pragma unroll
    for (int t = 0; t < 8; t++) {
        float bv = bfin[t * 16 + c];
#pragma unroll
        for (int r = 0; r < 4; r++) { acc2[0][t][r] = bv; acc2[1][t][r] = bv; }
    }
    const uint4* Wfh4 = (const uint4*)Wfh;
    const uint4* Wfl4 = (const uint4*)Wflo;
#pragma unroll
    for (int ks2 = 0; ks2 < 4; ks2++) {
#pragma unroll
        for (int t = 0; t < 8; t++) {
            int fi = (ks2 * 8 + t) * 64 + lane;
            bf16x8 bh = __builtin_bit_cast(bf16x8, Wfh4[fi]);
            bf16x8 blo = __builtin_bit_cast(bf16x8, Wfl4[fi]);
            acc2[0][t] = __builtin_amdgcn_mfma_f32_16x16x32_bf16(ah2[0][ks2], bh, acc2[0][t], 0, 0, 0);
            acc2[0][t] = __builtin_amdgcn_mfma_f32_16x16x32_bf16(al2[0][ks2], bh, acc2[0][t], 0, 0, 0);
            acc2[0][t] = __builtin_amdgcn_mfma_f32_16x16x32_bf16(ah2[0][ks2], blo, acc2[0][t], 0, 0, 0);
            acc2[1][t] = __builtin_amdgcn_mfma_f32_16x16x32_bf16(ah2[1][ks2], bh, acc2[1][t], 0, 0, 0);
            acc2[1][t] = __builtin_amdgcn_mfma_f32_16x16x32_bf16(al2[1][ks2], bh, acc2[1][t], 0, 0, 0);
            acc2[1][t] = __builtin_amdgcn_mfma_f32_16x16x32_bf16(ah2[1][ks2], blo, acc2[1][t], 0, 0, 0);
        }
    }

#pragma unroll
    for (int g = 0; g < 2; g++)
#pragma unroll
        for (int t = 0; t < 8; t++)
#pragma unroll
            for (int r = 0; r < 4; r++) {
                int row = R + g * 16 + q * 4 + r;
                if (row < N) out[(size_t)row * D + t * 16 + c] = acc2[g][t][r];
            }
}

extern "C" void kernel_launch(void* const* d_in, const int* in_sizes, int n_in,
                              void* d_out, int out_size, void* d_ws, size_t ws_size,
                              hipStream_t stream) {
    const float* x   = (const float*)d_in[0];
    const int*   ei  = (const int*)d_in[1];
    const float* W1l = (const float*)d_in[2];
    const float* b1  = (const float*)d_in[3];
    const float* W1r = (const float*)d_in[4];
    const float* W2l = (const float*)d_in[5];
    const float* b2  = (const float*)d_in[6];
    const float* W2r = (const float*)d_in[7];
    const float* Wf  = (const float*)d_in[8];
    const float* bf  = (const float*)d_in[9];
    float* out = (float*)d_out;

    int N = in_sizes[0] / D;
    int E = in_sizes[1] / 2;

    // ws: agg[N*D] f | inv[N] f | rs[N] i | cnt[N] i | cursor[N] i | bsum[256] i | csr[E] i | packW
    float* ws     = (float*)d_ws;
    float* agg    = ws;
    float* inv    = ws + (size_t)N * D;
    int*   rs     = (int*)(inv + N);
    int*   cnt    = rs + N;
    int*   cursor = cnt + N;
    int*   bsum   = cursor + N;
    int*   csr    = bsum + 256;
    unsigned short* pw = (unsigned short*)(csr + E);
    unsigned short* pW1lh = pw + 0 * 32768, *pW1ll = pW1lh + 16384;
    unsigned short* pW1rh = pw + 1 * 32768, *pW1rl = pW1rh + 16384;
    unsigned short* pW2lh = pw + 2 * 32768, *pW2ll = pW2lh + 16384;
    unsigned short* pW2rh = pw + 3 * 32768, *pW2rl = pW2rh + 16384;
    unsigned short* pWfh  = pw + 4 * 32768, *pWfl  = pWfh + 16384;

    int nb = (N + SCAN_B - 1) / SCAN_B;

    hipMemsetAsync(cnt, 0, (size_t)N * sizeof(int), stream);
    pack_kernel<<<40, 256, 0, stream>>>(W1l, W1r, W2l, W2r, Wf, pw);
    count_kernel<<<(E + 255) / 256, 256, 0, stream>>>(ei, E, cnt);
    scan_pass1<<<nb, SCAN_B, 0, stream>>>(cnt, rs, bsum, N);
    scan_pass2<<<1, SCAN_B, 0, stream>>>(bsum, nb);
    scan_pass3<<<nb, SCAN_B, 0, stream>>>(rs, cursor, bsum, cnt, inv, N);
    fill_kernel<<<(E + 255) / 256, 256, 0, stream>>>(ei, E, cursor, csr);

    int agg_blocks = (N * 32 + 255) / 256;
    int gemm_blocks = (N + 127) / 128;

    // layer 1 (h1 lives in d_out)
    aggregate_kernel<<<agg_blocks, 256, 0, stream>>>(x, csr, rs, cnt, inv, agg, N);
    mfma_gemm<0><<<gemm_blocks, 256, 0, stream>>>(agg, x, pW1lh, pW1ll, pW1rh, pW1rl, b1,
                                                  nullptr, nullptr, nullptr, out, N);

    // layer 2 + fused FC (reads h1 from d_out, overwrites d_out; per-block row regions disjoint)
    aggregate_kernel<<<agg_blocks, 256, 0, stream>>>(out, csr, rs, cnt, inv, agg, N);
    mfma_gemm<1><<<gemm_blocks, 256, 0, stream>>>(agg, out, pW2lh, pW2ll, pW2rh, pW2rl, b2,
                                                  pWfh, pWfl, bf, out, N);
}

// Round 10
// 307.868 us; speedup vs baseline: 1.0468x; 1.0468x over previous
//
#include <hip/hip_runtime.h>
#include <hip/hip_fp16.h>

#define D 128
#define SCAN_B 256

typedef __attribute__((ext_vector_type(8))) short bf16x8;
typedef __attribute__((ext_vector_type(4))) float f32x4;

__device__ __forceinline__ unsigned short f2bf(float f) {
    unsigned u = __float_as_uint(f);
    unsigned r = u + 0x7FFFu + ((u >> 16) & 1u);  // RNE
    return (unsigned short)(r >> 16);
}
__device__ __forceinline__ float bf2f(unsigned short h) {
    return __uint_as_float(((unsigned)h) << 16);
}

// ---- degree count ----
__global__ void count_kernel(const int* __restrict__ ei, int E, int* __restrict__ cnt) {
    int t = blockIdx.x * blockDim.x + threadIdx.x;
    if (t < E) atomicAdd(&cnt[ei[E + t]], 1);
}

// ---- hierarchical exclusive scan ----
__global__ void scan_pass1(const int* __restrict__ cnt, int* __restrict__ rs,
                           int* __restrict__ bsum, int N) {
    __shared__ int lds[SCAN_B];
    int tid = threadIdx.x;
    int i = blockIdx.x * SCAN_B + tid;
    int v = (i < N) ? cnt[i] : 0;
    lds[tid] = v;
    __syncthreads();
    for (int o = 1; o < SCAN_B; o <<= 1) {
        int t = (tid >= o) ? lds[tid - o] : 0;
        __syncthreads();
        lds[tid] += t;
        __syncthreads();
    }
    if (i < N) rs[i] = lds[tid] - v;
    if (tid == SCAN_B - 1) bsum[blockIdx.x] = lds[tid];
}

__global__ void scan_pass2(int* __restrict__ bsum, int nb) {
    __shared__ int lds[SCAN_B];
    int tid = threadIdx.x;
    int v = (tid < nb) ? bsum[tid] : 0;
    lds[tid] = v;
    __syncthreads();
    for (int o = 1; o < SCAN_B; o <<= 1) {
        int t = (tid >= o) ? lds[tid - o] : 0;
        __syncthreads();
        lds[tid] += t;
        __syncthreads();
    }
    if (tid < nb) bsum[tid] = lds[tid] - v;
}

__global__ void scan_pass3(int* __restrict__ rs, int* __restrict__ cursor,
                           const int* __restrict__ bsum, const int* __restrict__ cnt,
                           float* __restrict__ inv, int N) {
    int i = blockIdx.x * SCAN_B + threadIdx.x;
    if (i < N) {
        int v = rs[i] + bsum[blockIdx.x];
        rs[i] = v;
        cursor[i] = v;
        inv[i] = 1.0f / (float)max(cnt[i], 1);
    }
}

__global__ void fill_kernel(const int* __restrict__ ei, int E,
                            int* __restrict__ cursor, int* __restrict__ csr) {
    int e = blockIdx.x * blockDim.x + threadIdx.x;
    if (e < E) {
        int src = ei[e], dst = ei[E + e];
        int pos = atomicAdd(&cursor[dst], 1);
        csr[pos] = src;
    }
}

// ---- fp32 -> fp16 row cache (one thread per 8 elements) ----
__global__ void cvt_half_kernel(const float* __restrict__ x, __half* __restrict__ xh, int n8) {
    int i = blockIdx.x * blockDim.x + threadIdx.x;
    if (i >= n8) return;
    const float4* x4 = (const float4*)x;
    float4 a = x4[2 * i], b = x4[2 * i + 1];
    __half2 h0 = __floats2half2_rn(a.x, a.y);
    __half2 h1 = __floats2half2_rn(a.z, a.w);
    __half2 h2 = __floats2half2_rn(b.x, b.y);
    __half2 h3 = __floats2half2_rn(b.z, b.w);
    uint4 o;
    o.x = *(const unsigned*)&h0;
    o.y = *(const unsigned*)&h1;
    o.z = *(const unsigned*)&h2;
    o.w = *(const unsigned*)&h3;
    ((uint4*)xh)[i] = o;
}

__device__ __forceinline__ void acc8(uint4 v, float* s) {
    const __half2* h = reinterpret_cast<const __half2*>(&v);
    float2 f0 = __half22float2(h[0]);
    float2 f1 = __half22float2(h[1]);
    float2 f2 = __half22float2(h[2]);
    float2 f3 = __half22float2(h[3]);
    s[0] += f0.x; s[1] += f0.y; s[2] += f1.x; s[3] += f1.y;
    s[4] += f2.x; s[5] += f2.y; s[6] += f3.x; s[7] += f3.y;
}

// ---- gather-mean aggregate (fp16 source): 16 lanes/node, 8 cols/lane ----
__global__ void aggregate_kernel(const __half* __restrict__ xh, const int* __restrict__ csr,
                                 const int* __restrict__ rs, const int* __restrict__ cnt,
                                 const float* __restrict__ inv, float* __restrict__ agg,
                                 int N) {
    int t = blockIdx.x * blockDim.x + threadIdx.x;
    int node = t >> 4;
    int c = t & 15;
    if (node >= N) return;
    int deg = cnt[node];
    int st = rs[node];
    const uint4* x4 = (const uint4*)xh;  // 8 halfs per uint4; row = 16 uint4
    float s[8] = {0.f, 0.f, 0.f, 0.f, 0.f, 0.f, 0.f, 0.f};
    int i = 0;
    for (; i + 4 <= deg; i += 4) {
        int n0 = csr[st + i + 0], n1 = csr[st + i + 1];
        int n2 = csr[st + i + 2], n3 = csr[st + i + 3];
        uint4 v0 = x4[(size_t)n0 * 16 + c];
        uint4 v1 = x4[(size_t)n1 * 16 + c];
        uint4 v2 = x4[(size_t)n2 * 16 + c];
        uint4 v3 = x4[(size_t)n3 * 16 + c];
        acc8(v0, s); acc8(v1, s); acc8(v2, s); acc8(v3, s);
    }
    for (; i < deg; i++) {
        int n0 = csr[st + i];
        uint4 v0 = x4[(size_t)n0 * 16 + c];
        acc8(v0, s);
    }
    float iv = inv[node];
    float* dst = agg + (size_t)node * D + c * 8;
    ((float4*)dst)[0] = make_float4(s[0] * iv, s[1] * iv, s[2] * iv, s[3] * iv);
    ((float4*)dst)[1] = make_float4(s[4] * iv, s[5] * iv, s[6] * iv, s[7] * iv);
}

// ---- weight pack: fp32 [128k x 128n] -> bf16 hi/lo fragment-ordered ----
__global__ void pack_kernel(const float* __restrict__ W1l, const float* __restrict__ W1r,
                            const float* __restrict__ W2l, const float* __restrict__ W2r,
                            const float* __restrict__ Wf, unsigned short* __restrict__ pw) {
    int idx = blockIdx.x * blockDim.x + threadIdx.x;
    if (idx >= 5 * 2048) return;
    int w = idx >> 11;
    int r = idx & 2047;
    int ks = r >> 9;
    int t = (r >> 6) & 7;
    int lane = r & 63;
    int q = lane >> 4, n = lane & 15;
    const float* W = (w == 0) ? W1l : (w == 1) ? W1r : (w == 2) ? W2l : (w == 3) ? W2r : Wf;
    unsigned short* dh = pw + (size_t)w * 32768;
    unsigned short* dl = dh + 16384;
    int off = ((ks * 8 + t) * 64 + lane) * 8;
#pragma unroll
    for (int j = 0; j < 8; j++) {
        float v = W[(size_t)(ks * 32 + q * 8 + j) * D + t * 16 + n];
        unsigned short hb = f2bf(v);
        dh[off + j] = hb;
        dl[off + j] = f2bf(v - bf2f(hb));
    }
}

__device__ __forceinline__ void split8(const float* av, bf16x8& hi, bf16x8& lo) {
#pragma unroll
    for (int j = 0; j < 8; j++) {
        unsigned short hb = f2bf(av[j]);
        hi[j] = (short)hb;
        lo[j] = (short)f2bf(av[j] - bf2f(hb));
    }
}

// ---- barrier-free streaming MFMA GEMM, 16 rows/wave, 782-block grid ----
// C = relu(l2norm([agg|x] @ [Wl;Wr] + bl)) [@ Wf + bf]
template <int FUSE_FC>
__global__ __launch_bounds__(256) void mfma_gemm(
        const float* __restrict__ Aagg, const float* __restrict__ Ax,
        const unsigned short* __restrict__ W0h, const unsigned short* __restrict__ W0lo,
        const unsigned short* __restrict__ W1h, const unsigned short* __restrict__ W1lo,
        const float* __restrict__ bias,
        const unsigned short* __restrict__ Wfh, const unsigned short* __restrict__ Wflo,
        const float* __restrict__ bfin,
        float* __restrict__ out, __half* __restrict__ outh, int N) {
    __shared__ unsigned short Hs[FUSE_FC ? 4 * 4096 : 4];  // 8 KB/wave (FC only)

    const int tid = threadIdx.x;
    const int lane = tid & 63;
    const int wave = tid >> 6;
    const int c = lane & 15;   // A row-in-tile / C col-in-tile
    const int q = lane >> 4;   // quad
    const int R = blockIdx.x * 64 + wave * 16;  // wave's 16 rows

    int row0 = R + c;
    if (row0 >= N) row0 = N - 1;
    const size_t a_base = (size_t)row0 * D;

    f32x4 acc[8];
#pragma unroll
    for (int t = 0; t < 8; t++)
#pragma unroll
        for (int r = 0; r < 4; r++) acc[t][r] = 0.0f;

#pragma unroll
    for (int ks = 0; ks < 8; ks++) {
        const float* Asrc = (ks < 4) ? Aagg : Ax;
        const int kl = ks & 3;
        const int koff = kl * 32 + q * 8;
        float av[8];
        *((float4*)&av[0]) = *((const float4*)(Asrc + a_base + koff));
        *((float4*)&av[4]) = *((const float4*)(Asrc + a_base + koff + 4));
        bf16x8 ah, al;
        split8(av, ah, al);

        const uint4* Wh4 = (const uint4*)((ks < 4) ? W0h : W1h);
        const uint4* Wl4 = (const uint4*)((ks < 4) ? W0lo : W1lo);
#pragma unroll
        for (int t = 0; t < 8; t++) {
            int fi = (kl * 8 + t) * 64 + lane;
            bf16x8 bh = __builtin_bit_cast(bf16x8, Wh4[fi]);
            bf16x8 blo = __builtin_bit_cast(bf16x8, Wl4[fi]);
            acc[t] = __builtin_amdgcn_mfma_f32_16x16x32_bf16(ah, bh, acc[t], 0, 0, 0);
            acc[t] = __builtin_amdgcn_mfma_f32_16x16x32_bf16(al, bh, acc[t], 0, 0, 0);
            acc[t] = __builtin_amdgcn_mfma_f32_16x16x32_bf16(ah, blo, acc[t], 0, 0, 0);
        }
    }

    // epilogue: bias + per-row L2 norm + relu  (C layout: col=t*16+c, row=q*4+r)
#pragma unroll
    for (int t = 0; t < 8; t++) {
        float bv = bias[t * 16 + c];
#pragma unroll
        for (int r = 0; r < 4; r++) acc[t][r] += bv;
    }
#pragma unroll
    for (int r = 0; r < 4; r++) {
        float v = 0.0f;
#pragma unroll
        for (int t = 0; t < 8; t++) v += acc[t][r] * acc[t][r];
        v += __shfl_xor(v, 1, 16);
        v += __shfl_xor(v, 2, 16);
        v += __shfl_xor(v, 4, 16);
        v += __shfl_xor(v, 8, 16);
        float rn = 1.0f / fmaxf(sqrtf(v), 1e-12f);
#pragma unroll
        for (int t = 0; t < 8; t++) acc[t][r] = fmaxf(acc[t][r] * rn, 0.0f);
    }

    if (!FUSE_FC) {
#pragma unroll
        for (int t = 0; t < 8; t++)
#pragma unroll
            for (int r = 0; r < 4; r++) {
                int row = R + q * 4 + r;
                if (row < N) {
                    float v = acc[t][r];
                    out[(size_t)row * D + t * 16 + c] = v;
                    if (outh) outh[(size_t)row * D + t * 16 + c] = __float2half_rn(v);
                }
            }
        return;
    }

    // FC: per-wave LDS h-transform (C layout -> A-operand layout); wave-private,
    // DS pipe in-order per wave -> no barriers.
    unsigned short* Hw = &Hs[wave * 4096];
#pragma unroll
    for (int t = 0; t < 8; t++)
#pragma unroll
        for (int r = 0; r < 4; r++) {
            int row = q * 4 + r;
            int col = t * 16 + c;
            int ks2 = col >> 5, c32 = col & 31;
            int off = ((ks2 * 64) + (c32 >> 3) * 16 + row) * 8 + (c32 & 7);
            float hv = acc[t][r];
            unsigned short hb = f2bf(hv);
            Hw[off] = hb;
            Hw[2048 + off] = f2bf(hv - bf2f(hb));
        }

    f32x4 acc2[8];
#pragma unroll
    for (int t = 0; t < 8; t++) {
        float bv = bfin[t * 16 + c];
#pragma unroll
        for (int r = 0; r < 4; r++) acc2[t][r] = bv;
    }
    const uint4* Wfh4 = (const uint4*)Wfh;
    const uint4* Wfl4 = (const uint4*)Wflo;
#pragma unroll
    for (int ks2 = 0; ks2 < 4; ks2++) {
        bf16x8 ah2 = __builtin_bit_cast(bf16x8, ((const uint4*)Hw)[ks2 * 64 + lane]);
        bf16x8 al2 = __builtin_bit_cast(bf16x8, ((const uint4*)(Hw + 2048))[ks2 * 64 + lane]);
#pragma unroll
        for (int t = 0; t < 8; t++) {
            int fi = (ks2 * 8 + t) * 64 + lane;
            bf16x8 bh = __builtin_bit_cast(bf16x8, Wfh4[fi]);
            bf16x8 blo = __builtin_bit_cast(bf16x8, Wfl4[fi]);
            acc2[t] = __builtin_amdgcn_mfma_f32_16x16x32_bf16(ah2, bh, acc2[t], 0, 0, 0);
            acc2[t] = __builtin_amdgcn_mfma_f32_16x16x32_bf16(al2, bh, acc2[t], 0, 0, 0);
            acc2[t] = __builtin_amdgcn_mfma_f32_16x16x32_bf16(ah2, blo, acc2[t], 0, 0, 0);
        }
    }

#pragma unroll
    for (int t = 0; t < 8; t++)
#pragma unroll
        for (int r = 0; r < 4; r++) {
            int row = R + q * 4 + r;
            if (row < N) out[(size_t)row * D + t * 16 + c] = acc2[t][r];
        }
}

extern "C" void kernel_launch(void* const* d_in, const int* in_sizes, int n_in,
                              void* d_out, int out_size, void* d_ws, size_t ws_size,
                              hipStream_t stream) {
    const float* x   = (const float*)d_in[0];
    const int*   ei  = (const int*)d_in[1];
    const float* W1l = (const float*)d_in[2];
    const float* b1  = (const float*)d_in[3];
    const float* W1r = (const float*)d_in[4];
    const float* W2l = (const float*)d_in[5];
    const float* b2  = (const float*)d_in[6];
    const float* W2r = (const float*)d_in[7];
    const float* Wf  = (const float*)d_in[8];
    const float* bf  = (const float*)d_in[9];
    float* out = (float*)d_out;

    int N = in_sizes[0] / D;
    int E = in_sizes[1] / 2;

    // ws: agg[N*D] f | inv[N] f | rs[N] i | cnt[N] i | cursor[N] i | bsum[256] i |
    //     csr[E] i | pw[5*32768] ush | hb[N*D] half
    float* ws     = (float*)d_ws;
    float* agg    = ws;
    float* inv    = ws + (size_t)N * D;
    int*   rs     = (int*)(inv + N);
    int*   cnt    = rs + N;
    int*   cursor = cnt + N;
    int*   bsum   = cursor + N;
    int*   csr    = bsum + 256;
    unsigned short* pw = (unsigned short*)(csr + E);
    unsigned short* pW1lh = pw + 0 * 32768, *pW1ll = pW1lh + 16384;
    unsigned short* pW1rh = pw + 1 * 32768, *pW1rl = pW1rh + 16384;
    unsigned short* pW2lh = pw + 2 * 32768, *pW2ll = pW2lh + 16384;
    unsigned short* pW2rh = pw + 3 * 32768, *pW2rl = pW2rh + 16384;
    unsigned short* pWfh  = pw + 4 * 32768, *pWfl  = pWfh + 16384;
    __half* hb = (__half*)(pw + 5 * 32768);  // fp16 row cache (x, then h1)

    int nb = (N + SCAN_B - 1) / SCAN_B;

    hipMemsetAsync(cnt, 0, (size_t)N * sizeof(int), stream);
    pack_kernel<<<40, 256, 0, stream>>>(W1l, W1r, W2l, W2r, Wf, pw);
    int n8 = N * 16;
    cvt_half_kernel<<<(n8 + 255) / 256, 256, 0, stream>>>(x, hb, n8);
    count_kernel<<<(E + 255) / 256, 256, 0, stream>>>(ei, E, cnt);
    scan_pass1<<<nb, SCAN_B, 0, stream>>>(cnt, rs, bsum, N);
    scan_pass2<<<1, SCAN_B, 0, stream>>>(bsum, nb);
    scan_pass3<<<nb, SCAN_B, 0, stream>>>(rs, cursor, bsum, cnt, inv, N);
    fill_kernel<<<(E + 255) / 256, 256, 0, stream>>>(ei, E, cursor, csr);

    int agg_blocks = (N * 16 + 255) / 256;
    int gemm_blocks = (N + 63) / 64;

    // layer 1 (h1 fp32 in d_out, fp16 copy in hb)
    aggregate_kernel<<<agg_blocks, 256, 0, stream>>>(hb, csr, rs, cnt, inv, agg, N);
    mfma_gemm<0><<<gemm_blocks, 256, 0, stream>>>(agg, x, pW1lh, pW1ll, pW1rh, pW1rl, b1,
                                                  nullptr, nullptr, nullptr, out, hb, N);

    // layer 2 + fused FC
    aggregate_kernel<<<agg_blocks, 256, 0, stream>>>(hb, csr, rs, cnt, inv, agg, N);
    mfma_gemm<1><<<gemm_blocks, 256, 0, stream>>>(agg, out, pW2lh, pW2ll, pW2rh, pW2rl, b2,
                                                  pWfh, pWfl, bf, out, nullptr, N);
}

// Round 11
// 289.468 us; speedup vs baseline: 1.1133x; 1.0636x over previous
//
#include <hip/hip_runtime.h>
#include <hip/hip_fp16.h>

#define D 128
#define SCAN_B 256
#define HLD 136   // h LDS row stride (ushorts): pad -> 2-way-max bank aliasing

typedef __attribute__((ext_vector_type(8))) short bf16x8;
typedef __attribute__((ext_vector_type(4))) float f32x4;

__device__ __forceinline__ unsigned short f2bf(float f) {
    unsigned u = __float_as_uint(f);
    unsigned r = u + 0x7FFFu + ((u >> 16) & 1u);  // RNE
    return (unsigned short)(r >> 16);
}
__device__ __forceinline__ float bf2f(unsigned short h) {
    return __uint_as_float(((unsigned)h) << 16);
}

// ---- degree count ----
__global__ void count_kernel(const int* __restrict__ ei, int E, int* __restrict__ cnt) {
    int t = blockIdx.x * blockDim.x + threadIdx.x;
    if (t < E) atomicAdd(&cnt[ei[E + t]], 1);
}

// ---- hierarchical exclusive scan ----
__global__ void scan_pass1(const int* __restrict__ cnt, int* __restrict__ rs,
                           int* __restrict__ bsum, int N) {
    __shared__ int lds[SCAN_B];
    int tid = threadIdx.x;
    int i = blockIdx.x * SCAN_B + tid;
    int v = (i < N) ? cnt[i] : 0;
    lds[tid] = v;
    __syncthreads();
    for (int o = 1; o < SCAN_B; o <<= 1) {
        int t = (tid >= o) ? lds[tid - o] : 0;
        __syncthreads();
        lds[tid] += t;
        __syncthreads();
    }
    if (i < N) rs[i] = lds[tid] - v;
    if (tid == SCAN_B - 1) bsum[blockIdx.x] = lds[tid];
}

__global__ void scan_pass2(int* __restrict__ bsum, int nb) {
    __shared__ int lds[SCAN_B];
    int tid = threadIdx.x;
    int v = (tid < nb) ? bsum[tid] : 0;
    lds[tid] = v;
    __syncthreads();
    for (int o = 1; o < SCAN_B; o <<= 1) {
        int t = (tid >= o) ? lds[tid - o] : 0;
        __syncthreads();
        lds[tid] += t;
        __syncthreads();
    }
    if (tid < nb) bsum[tid] = lds[tid] - v;
}

__global__ void scan_pass3(int* __restrict__ rs, int* __restrict__ cursor,
                           const int* __restrict__ bsum, const int* __restrict__ cnt,
                           float* __restrict__ inv, int N) {
    int i = blockIdx.x * SCAN_B + threadIdx.x;
    if (i < N) {
        int v = rs[i] + bsum[blockIdx.x];
        rs[i] = v;
        cursor[i] = v;
        inv[i] = 1.0f / (float)max(cnt[i], 1);
    }
}

__global__ void fill_kernel(const int* __restrict__ ei, int E,
                            int* __restrict__ cursor, int* __restrict__ csr) {
    int e = blockIdx.x * blockDim.x + threadIdx.x;
    if (e < E) {
        int src = ei[e], dst = ei[E + e];
        int pos = atomicAdd(&cursor[dst], 1);
        csr[pos] = src;
    }
}

// ---- fp32 -> fp16 row cache ----
__global__ void cvt_half_kernel(const float* __restrict__ x, __half* __restrict__ xh, int n8) {
    int i = blockIdx.x * blockDim.x + threadIdx.x;
    if (i >= n8) return;
    const float4* x4 = (const float4*)x;
    float4 a = x4[2 * i], b = x4[2 * i + 1];
    __half2 h0 = __floats2half2_rn(a.x, a.y);
    __half2 h1 = __floats2half2_rn(a.z, a.w);
    __half2 h2 = __floats2half2_rn(b.x, b.y);
    __half2 h3 = __floats2half2_rn(b.z, b.w);
    uint4 o;
    o.x = *(const unsigned*)&h0;
    o.y = *(const unsigned*)&h1;
    o.z = *(const unsigned*)&h2;
    o.w = *(const unsigned*)&h3;
    ((uint4*)xh)[i] = o;
}

__device__ __forceinline__ void acc8(uint4 v, float* s) {
    const __half2* h = reinterpret_cast<const __half2*>(&v);
    float2 f0 = __half22float2(h[0]);
    float2 f1 = __half22float2(h[1]);
    float2 f2 = __half22float2(h[2]);
    float2 f3 = __half22float2(h[3]);
    s[0] += f0.x; s[1] += f0.y; s[2] += f1.x; s[3] += f1.y;
    s[4] += f2.x; s[5] += f2.y; s[6] += f3.x; s[7] += f3.y;
}

// ---- gather-mean aggregate (fp16 source): 16 lanes/node, 8 cols/lane ----
__global__ void aggregate_kernel(const __half* __restrict__ xh, const int* __restrict__ csr,
                                 const int* __restrict__ rs, const int* __restrict__ cnt,
                                 const float* __restrict__ inv, float* __restrict__ agg,
                                 int N) {
    int t = blockIdx.x * blockDim.x + threadIdx.x;
    int node = t >> 4;
    int c = t & 15;
    if (node >= N) return;
    int deg = cnt[node];
    int st = rs[node];
    const uint4* x4 = (const uint4*)xh;
    float s[8] = {0.f, 0.f, 0.f, 0.f, 0.f, 0.f, 0.f, 0.f};
    int i = 0;
    for (; i + 4 <= deg; i += 4) {
        int n0 = csr[st + i + 0], n1 = csr[st + i + 1];
        int n2 = csr[st + i + 2], n3 = csr[st + i + 3];
        uint4 v0 = x4[(size_t)n0 * 16 + c];
        uint4 v1 = x4[(size_t)n1 * 16 + c];
        uint4 v2 = x4[(size_t)n2 * 16 + c];
        uint4 v3 = x4[(size_t)n3 * 16 + c];
        acc8(v0, s); acc8(v1, s); acc8(v2, s); acc8(v3, s);
    }
    for (; i < deg; i++) {
        int n0 = csr[st + i];
        uint4 v0 = x4[(size_t)n0 * 16 + c];
        acc8(v0, s);
    }
    float iv = inv[node];
    float* dst = agg + (size_t)node * D + c * 8;
    ((float4*)dst)[0] = make_float4(s[0] * iv, s[1] * iv, s[2] * iv, s[3] * iv);
    ((float4*)dst)[1] = make_float4(s[4] * iv, s[5] * iv, s[6] * iv, s[7] * iv);
}

// ---- weight pack: fp32 [128k x 128n] -> bf16 hi/lo fragment-ordered ----
__global__ void pack_kernel(const float* __restrict__ W1l, const float* __restrict__ W1r,
                            const float* __restrict__ W2l, const float* __restrict__ W2r,
                            const float* __restrict__ Wf, unsigned short* __restrict__ pw) {
    int idx = blockIdx.x * blockDim.x + threadIdx.x;
    if (idx >= 5 * 2048) return;
    int w = idx >> 11;
    int r = idx & 2047;
    int ks = r >> 9;
    int t = (r >> 6) & 7;
    int lane = r & 63;
    int q = lane >> 4, n = lane & 15;
    const float* W = (w == 0) ? W1l : (w == 1) ? W1r : (w == 2) ? W2l : (w == 3) ? W2r : Wf;
    unsigned short* dh = pw + (size_t)w * 32768;
    unsigned short* dl = dh + 16384;
    int off = ((ks * 8 + t) * 64 + lane) * 8;
#pragma unroll
    for (int j = 0; j < 8; j++) {
        float v = W[(size_t)(ks * 32 + q * 8 + j) * D + t * 16 + n];
        unsigned short hb = f2bf(v);
        dh[off + j] = hb;
        dl[off + j] = f2bf(v - bf2f(hb));
    }
}

__device__ __forceinline__ void split8(const float* av, bf16x8& hi, bf16x8& lo) {
#pragma unroll
    for (int j = 0; j < 8; j++) {
        unsigned short hb = f2bf(av[j]);
        hi[j] = (short)hb;
        lo[j] = (short)f2bf(av[j] - bf2f(hb));
    }
}

// ---- column-split streaming MFMA GEMM ----
// block = 4 waves = 2 row-groups (rg) x 2 col-groups (cg).
// wave: 16 rows x 64 cols (4 t-tiles). grid = ceil(N/32). K=256.
// C = relu(l2norm([agg|x] @ [Wl;Wr] + bl)) [@ Wf + bf]
template <int FUSE_FC>
__global__ __launch_bounds__(256) void mfma_gemm(
        const float* __restrict__ Aagg, const float* __restrict__ Ax,
        const unsigned short* __restrict__ W0h, const unsigned short* __restrict__ W0lo,
        const unsigned short* __restrict__ W1h, const unsigned short* __restrict__ W1lo,
        const float* __restrict__ bias,
        const unsigned short* __restrict__ Wfh, const unsigned short* __restrict__ Wflo,
        const float* __restrict__ bfin,
        float* __restrict__ out, __half* __restrict__ outh, int N) {
    __shared__ float normbuf[2][2][16];                                  // [rg][cg][row]
    __shared__ unsigned short Hs[FUSE_FC ? 2 * 2 * 16 * HLD : 4];        // per rg: hi[16][HLD], lo[16][HLD]

    const int tid = threadIdx.x;
    const int lane = tid & 63;
    const int wave = tid >> 6;
    const int rg = wave >> 1;
    const int cg = wave & 1;
    const int c = lane & 15;
    const int q = lane >> 4;
    const int R = blockIdx.x * 32 + rg * 16;

    int row0 = R + c;
    if (row0 >= N) row0 = N - 1;
    const size_t a_base = (size_t)row0 * D;

    f32x4 acc[4];
#pragma unroll
    for (int t = 0; t < 4; t++)
#pragma unroll
        for (int r = 0; r < 4; r++) acc[t][r] = 0.0f;

#pragma unroll
    for (int ks = 0; ks < 8; ks++) {
        const float* Asrc = (ks < 4) ? Aagg : Ax;
        const int kl = ks & 3;
        const int koff = kl * 32 + q * 8;
        float av[8];
        *((float4*)&av[0]) = *((const float4*)(Asrc + a_base + koff));
        *((float4*)&av[4]) = *((const float4*)(Asrc + a_base + koff + 4));
        bf16x8 ah, al;
        split8(av, ah, al);

        const uint4* Wh4 = (const uint4*)((ks < 4) ? W0h : W1h);
        const uint4* Wl4 = (const uint4*)((ks < 4) ? W0lo : W1lo);
#pragma unroll
        for (int t = 0; t < 4; t++) {
            int fi = (kl * 8 + cg * 4 + t) * 64 + lane;
            bf16x8 bh = __builtin_bit_cast(bf16x8, Wh4[fi]);
            bf16x8 blo = __builtin_bit_cast(bf16x8, Wl4[fi]);
            acc[t] = __builtin_amdgcn_mfma_f32_16x16x32_bf16(ah, bh, acc[t], 0, 0, 0);
            acc[t] = __builtin_amdgcn_mfma_f32_16x16x32_bf16(al, bh, acc[t], 0, 0, 0);
            acc[t] = __builtin_amdgcn_mfma_f32_16x16x32_bf16(ah, blo, acc[t], 0, 0, 0);
        }
    }

    // bias (wave's cols are (cg*4+t)*16 + c)
#pragma unroll
    for (int t = 0; t < 4; t++) {
        float bv = bias[(cg * 4 + t) * 16 + c];
#pragma unroll
        for (int r = 0; r < 4; r++) acc[t][r] += bv;
    }
    // partial sumsq per row (this wave's 64 cols), 16-lane reduce
    float vr[4];
#pragma unroll
    for (int r = 0; r < 4; r++) {
        float v = 0.0f;
#pragma unroll
        for (int t = 0; t < 4; t++) v += acc[t][r] * acc[t][r];
        v += __shfl_xor(v, 1, 16);
        v += __shfl_xor(v, 2, 16);
        v += __shfl_xor(v, 4, 16);
        v += __shfl_xor(v, 8, 16);
        vr[r] = v;
    }
    if (c == 0) {
#pragma unroll
        for (int r = 0; r < 4; r++) normbuf[rg][cg][q * 4 + r] = vr[r];
    }
    __syncthreads();
#pragma unroll
    for (int r = 0; r < 4; r++) {
        int row = q * 4 + r;
        float tot = normbuf[rg][0][row] + normbuf[rg][1][row];
        float rn = 1.0f / fmaxf(sqrtf(tot), 1e-12f);
#pragma unroll
        for (int t = 0; t < 4; t++) acc[t][r] = fmaxf(acc[t][r] * rn, 0.0f);
    }

    if (!FUSE_FC) {
#pragma unroll
        for (int t = 0; t < 4; t++)
#pragma unroll
            for (int r = 0; r < 4; r++) {
                int row = R + q * 4 + r;
                if (row < N) {
                    float v = acc[t][r];
                    size_t idx = (size_t)row * D + (cg * 4 + t) * 16 + c;
                    out[idx] = v;
                    if (outh) outh[idx] = __float2half_rn(v);
                }
            }
        return;
    }

    // FC: write h (bf16 hi/lo) to this rg's shared LDS, both cg waves fill 128 cols
    unsigned short* Hhi = &Hs[rg * 2 * 16 * HLD];
    unsigned short* Hlo = Hhi + 16 * HLD;
#pragma unroll
    for (int t = 0; t < 4; t++)
#pragma unroll
        for (int r = 0; r < 4; r++) {
            int row = q * 4 + r;
            int col = (cg * 4 + t) * 16 + c;
            float hv = acc[t][r];
            unsigned short hb = f2bf(hv);
            Hhi[row * HLD + col] = hb;
            Hlo[row * HLD + col] = f2bf(hv - bf2f(hb));
        }
    __syncthreads();

    f32x4 acc2[4];
#pragma unroll
    for (int t = 0; t < 4; t++) {
        float bv = bfin[(cg * 4 + t) * 16 + c];
#pragma unroll
        for (int r = 0; r < 4; r++) acc2[t][r] = bv;
    }
    const uint4* Wfh4 = (const uint4*)Wfh;
    const uint4* Wfl4 = (const uint4*)Wflo;
#pragma unroll
    for (int ks2 = 0; ks2 < 4; ks2++) {
        // A-frag: h[m=c][k=ks2*32+q*8+j] — 16 B aligned (HLD even, *2B)
        bf16x8 ah2 = __builtin_bit_cast(bf16x8, *(const uint4*)&Hhi[c * HLD + ks2 * 32 + q * 8]);
        bf16x8 al2 = __builtin_bit_cast(bf16x8, *(const uint4*)&Hlo[c * HLD + ks2 * 32 + q * 8]);
#pragma unroll
        for (int t = 0; t < 4; t++) {
            int fi = (ks2 * 8 + cg * 4 + t) * 64 + lane;
            bf16x8 bh = __builtin_bit_cast(bf16x8, Wfh4[fi]);
            bf16x8 blo = __builtin_bit_cast(bf16x8, Wfl4[fi]);
            acc2[t] = __builtin_amdgcn_mfma_f32_16x16x32_bf16(ah2, bh, acc2[t], 0, 0, 0);
            acc2[t] = __builtin_amdgcn_mfma_f32_16x16x32_bf16(al2, bh, acc2[t], 0, 0, 0);
            acc2[t] = __builtin_amdgcn_mfma_f32_16x16x32_bf16(ah2, blo, acc2[t], 0, 0, 0);
        }
    }

#pragma unroll
    for (int t = 0; t < 4; t++)
#pragma unroll
        for (int r = 0; r < 4; r++) {
            int row = R + q * 4 + r;
            if (row < N) out[(size_t)row * D + (cg * 4 + t) * 16 + c] = acc2[t][r];
        }
}

extern "C" void kernel_launch(void* const* d_in, const int* in_sizes, int n_in,
                              void* d_out, int out_size, void* d_ws, size_t ws_size,
                              hipStream_t stream) {
    const float* x   = (const float*)d_in[0];
    const int*   ei  = (const int*)d_in[1];
    const float* W1l = (const float*)d_in[2];
    const float* b1  = (const float*)d_in[3];
    const float* W1r = (const float*)d_in[4];
    const float* W2l = (const float*)d_in[5];
    const float* b2  = (const float*)d_in[6];
    const float* W2r = (const float*)d_in[7];
    const float* Wf  = (const float*)d_in[8];
    const float* bf  = (const float*)d_in[9];
    float* out = (float*)d_out;

    int N = in_sizes[0] / D;
    int E = in_sizes[1] / 2;

    // ws: agg[N*D] f | inv[N] f | rs[N] i | cnt[N] i | cursor[N] i | bsum[256] i |
    //     csr[E] i | pw[5*32768] ush | hb[N*D] half
    float* ws     = (float*)d_ws;
    float* agg    = ws;
    float* inv    = ws + (size_t)N * D;
    int*   rs     = (int*)(inv + N);
    int*   cnt    = rs + N;
    int*   cursor = cnt + N;
    int*   bsum   = cursor + N;
    int*   csr    = bsum + 256;
    unsigned short* pw = (unsigned short*)(csr + E);
    unsigned short* pW1lh = pw + 0 * 32768, *pW1ll = pW1lh + 16384;
    unsigned short* pW1rh = pw + 1 * 32768, *pW1rl = pW1rh + 16384;
    unsigned short* pW2lh = pw + 2 * 32768, *pW2ll = pW2lh + 16384;
    unsigned short* pW2rh = pw + 3 * 32768, *pW2rl = pW2rh + 16384;
    unsigned short* pWfh  = pw + 4 * 32768, *pWfl  = pWfh + 16384;
    __half* hb = (__half*)(pw + 5 * 32768);  // fp16 row cache (x, then h1)

    int nb = (N + SCAN_B - 1) / SCAN_B;

    hipMemsetAsync(cnt, 0, (size_t)N * sizeof(int), stream);
    pack_kernel<<<40, 256, 0, stream>>>(W1l, W1r, W2l, W2r, Wf, pw);
    int n8 = N * 16;
    cvt_half_kernel<<<(n8 + 255) / 256, 256, 0, stream>>>(x, hb, n8);
    count_kernel<<<(E + 255) / 256, 256, 0, stream>>>(ei, E, cnt);
    scan_pass1<<<nb, SCAN_B, 0, stream>>>(cnt, rs, bsum, N);
    scan_pass2<<<1, SCAN_B, 0, stream>>>(bsum, nb);
    scan_pass3<<<nb, SCAN_B, 0, stream>>>(rs, cursor, bsum, cnt, inv, N);
    fill_kernel<<<(E + 255) / 256, 256, 0, stream>>>(ei, E, cursor, csr);

    int agg_blocks = (N * 16 + 255) / 256;
    int gemm_blocks = (N + 31) / 32;

    // layer 1 (h1 fp32 in d_out, fp16 copy in hb)
    aggregate_kernel<<<agg_blocks, 256, 0, stream>>>(hb, csr, rs, cnt, inv, agg, N);
    mfma_gemm<0><<<gemm_blocks, 256, 0, stream>>>(agg, x, pW1lh, pW1ll, pW1rh, pW1rl, b1,
                                                  nullptr, nullptr, nullptr, out, hb, N);

    // layer 2 + fused FC
    aggregate_kernel<<<agg_blocks, 256, 0, stream>>>(hb, csr, rs, cnt, inv, agg, N);
    mfma_gemm<1><<<gemm_blocks, 256, 0, stream>>>(agg, out, pW2lh, pW2ll, pW2rh, pW2rl, b2,
                                                  pWfh, pWfl, bf, out, nullptr, N);
}